// Round 10
// baseline (425.326 us; speedup 1.0000x reference)
//
#include <hip/hip_runtime.h>
#include <hip/hip_fp16.h>
#include <math.h>

#define NU 50000
#define NI 50000
#define NT 100000
#define DD 64
#define NBATCH 4096
#define INV_TEMP 5.0f
#define EPS_ 0.2f

#define CBR 128                            // rows per coarse bucket
#define CBR_SH 7
#define NCB ((NT + CBR - 1) / CBR)         // 782
#define CAP 4800                           // fixed edge capacity per bucket (mean 4096, ~11 sigma)
#define TILE 8192                          // edges per phase-1 block (staged in LDS)
#define NWSUM ((NCB + 63) / 64)            // 13
#define ND ((long long)NT * DD)            // 6,400,000
#define BPR_BLOCKS (NBATCH / 4)            // 1024 partials

typedef _Float16 half8 __attribute__((ext_vector_type(8)));
typedef float floatx4 __attribute__((ext_vector_type(4)));
typedef float fvec4 __attribute__((ext_vector_type(4)));   // builtin-compatible float4

// ---------------- phase 1: block-level counting sort into fixed-capacity coarse buckets ----------------
__global__ __launch_bounds__(1024, 8) void coarse_bin_kernel(
        const int* __restrict__ rows, const int* __restrict__ cols,
        const float* __restrict__ vals, int E,
        int* __restrict__ ccur, int2* __restrict__ bedges) {
    __shared__ int  sx[TILE];       // (rl<<24)|(col<<7)       32 KB
    __shared__ uint svc[TILE];      // (cb<<16)|half(val)      32 KB
    __shared__ int  h[NCB];         // hist -> lcur
    __shared__ int  lstart[NCB];    // exclusive scan
    __shared__ int  gbase[NCB];     // global run base
    __shared__ int  wsum[NWSUM];
    int t = threadIdx.x;   // 1024
    for (int k = t; k < NCB; k += 1024) h[k] = 0;
    __syncthreads();
    int base = blockIdx.x * TILE;
    int cnt = min(TILE, E - base);
    // pass A: load tile into registers + LDS histogram
    int   r_[8];
    int   c_[8];
    float v_[8];
    #pragma unroll
    for (int it = 0; it < 8; ++it) {
        int i = it * 1024 + t;
        bool ok = i < cnt;
        int e = base + i;
        r_[it] = ok ? rows[e] : 0;
        c_[it] = ok ? cols[e] : 0;
        v_[it] = ok ? vals[e] : 0.f;
        if (ok) atomicAdd(&h[r_[it] >> CBR_SH], 1);
    }
    __syncthreads();
    // exclusive scan of h[0..NCB) -> lstart; reserve global runs
    int lane = t & 63, wid = t >> 6;
    int v = (t < NCB) ? h[t] : 0;
    int x = v;
    #pragma unroll
    for (int o = 1; o < 64; o <<= 1) { int y = __shfl_up(x, o); if (lane >= o) x += y; }
    if (lane == 63 && wid < NWSUM) wsum[wid] = x;
    __syncthreads();
    if (t == 0) {
        int s = 0;
        #pragma unroll
        for (int k = 0; k < NWSUM; ++k) { int tmp = wsum[k]; wsum[k] = s; s += tmp; }
    }
    __syncthreads();
    if (t < NCB) {
        int ex = x - v + wsum[wid];
        lstart[t] = ex;
        gbase[t] = t * CAP + (v ? atomicAdd(&ccur[t], v) : 0);
        h[t] = ex;   // becomes lcur
    }
    __syncthreads();
    // pass B: scatter into LDS (counting-sort placement)
    #pragma unroll
    for (int it = 0; it < 8; ++it) {
        int i = it * 1024 + t;
        if (i < cnt) {
            int r = r_[it];
            int cb = r >> CBR_SH;
            int p = atomicAdd(&h[cb], 1);
            sx[p] = ((r & (CBR - 1)) << 24) | (c_[it] << 7);
            __half hv = __float2half(v_[it]);
            ushort hb = *reinterpret_cast<ushort*>(&hv);
            svc[p] = ((uint)cb << 16) | (uint)hb;
        }
    }
    __syncthreads();
    // pass C: coalesced write-out in staged (bucket-sorted) order
    for (int i = t; i < cnt; i += 1024) {
        uint vc = svc[i];
        int cb = (int)(vc >> 16);
        uint hb = vc & 0xFFFFu;
        int dst = gbase[cb] + (i - lstart[cb]);
        bedges[dst] = make_int2(sx[i], (int)(hb | (hb << 16)));
    }
}

// ---------------- phase 2: per-bucket row sort, LDS-staged for coalesced writeout ----------------
__global__ __launch_bounds__(512, 8) void fine_sort_kernel(
        const int* __restrict__ ccur, const int2* __restrict__ bedges,
        int2* __restrict__ edges, int* __restrict__ rstart,
        int* __restrict__ deg) {
    __shared__ int2 sedge[CAP];     // 38.4 KB staged sorted bucket
    __shared__ int h[CBR];
    __shared__ int lcur[CBR];
    __shared__ int wsum[CBR / 64];
    int b = blockIdx.x;
    int t = threadIdx.x;   // 512
    int r0 = b * CBR;
    int nrows = min(CBR, NT - r0);
    if (t < CBR) h[t] = 0;
    __syncthreads();
    int e0 = b * CAP;
    int ec = ccur[b];
    int e1 = e0 + ec;
    for (int k = e0 + t; k < e1; k += 512) atomicAdd(&h[((uint)bedges[k].x) >> 24], 1);
    __syncthreads();
    int v = 0, x = 0;
    int lane = t & 63, wid = t >> 6;
    if (t < CBR) {
        v = h[t];
        x = v;
        #pragma unroll
        for (int o = 1; o < 64; o <<= 1) { int y = __shfl_up(x, o); if (lane >= o) x += y; }
        if (lane == 63) wsum[wid] = x;
    }
    __syncthreads();
    if (t == 0) {
        int s = 0;
        #pragma unroll
        for (int k = 0; k < CBR / 64; ++k) { int tmp = wsum[k]; wsum[k] = s; s += tmp; }
    }
    __syncthreads();
    if (t < CBR) {
        int ex = x - v + wsum[wid];          // local (0-based) start
        if (t < nrows) { rstart[r0 + t] = e0 + ex; deg[r0 + t] = v; }
        lcur[t] = ex;
    }
    __syncthreads();
    // scatter into LDS in row-sorted order
    for (int k = e0 + t; k < e1; k += 512) {
        int2 ed = bedges[k];
        int rl = (int)(((uint)ed.x) >> 24);
        int p = atomicAdd(&lcur[rl], 1);
        if (p < CAP) sedge[p] = make_int2(ed.x & 0xFFFFFF, ed.y);
    }
    __syncthreads();
    // fully-coalesced streaming writeout
    for (int i = t; i < ec; i += 512) edges[e0 + i] = sedge[i];
}

// ---------------- fp32 concat -> fp16 (4 elems/thread) ----------------
__global__ void concat_half_kernel(const float* __restrict__ u, const float* __restrict__ it,
                                   __half* __restrict__ x0) {
    long long i = ((long long)blockIdx.x * 256 + threadIdx.x) * 4;
    if (i >= ND) return;
    long long half1 = (long long)NU * DD;
    float4 v = (i < half1) ? *(const float4*)(u + i) : *(const float4*)(it + (i - half1));
    __half2 h01 = __floats2half2_rn(v.x, v.y);
    __half2 h23 = __floats2half2_rn(v.z, v.w);
    uint2 q;
    q.x = *reinterpret_cast<uint*>(&h01);
    q.y = *reinterpret_cast<uint*>(&h23);
    *(uint2*)((ushort*)x0 + i) = q;
}

// ---------------- SpMM: 2 rows per wave, 8 staged edges/group; edges+noise NON-TEMPORAL ----------------
// Single-use streams (edges 25.6MB, noise 25.6MB) deprioritize L2 so the x-gather's 12.8MB
// working set keeps residency (current hit rate ~70%; streamed lines evict reusable x lines).
__global__ void spmm_csr_kernel(const int* __restrict__ rstart, const int* __restrict__ deg,
                                const int2* __restrict__ edges,
                                const __half* __restrict__ x, const float* __restrict__ noise,
                                __half* __restrict__ y) {
    int gid = blockIdx.x * blockDim.x + threadIdx.x;
    int row = gid >> 5;        // one row per 32 lanes
    int l32 = gid & 31;
    int group = l32 >> 3;      // 0..3: edge-slot group within the row
    int sub = l32 & 7;         // dims sub*8 .. sub*8+7
    int subo = sub << 4;       // byte offset of this lane's 16B segment
    if (row >= NT) return;
    int s0 = rstart[row];
    int dg = deg[row];
    int dgl = dg - group;      // edge base+group+4j valid iff base+4j < dgl
    const char* xb = (const char*)x;
    const long long* edq = (const long long*)edges;
    __half2 acc0 = __half2(__half(0.f), __half(0.f));
    __half2 acc1 = acc0, acc2 = acc0, acc3 = acc0;
    for (int base = 0; base < dg; base += 32) {
        long long eq[8];
        #pragma unroll
        for (int j = 0; j < 8; ++j) {
            eq[j] = __builtin_nontemporal_load(&edq[s0 + min(base + group + 4 * j, dg - 1)]);
        }
        uint4 q[8];
        #pragma unroll
        for (int j = 0; j < 8; ++j) {
            q[j] = *(const uint4*)(xb + (uint)((int)(eq[j] & 0xFFFFFFFFll) + subo));  // cached: x is the reuse set
        }
        #pragma unroll
        for (int j = 0; j < 8; ++j) {
            int vb = (base + 4 * j < dgl) ? (int)(eq[j] >> 32) : 0;
            __half2 vv = *reinterpret_cast<__half2*>(&vb);
            acc0 = __hfma2(*reinterpret_cast<__half2*>(&q[j].x), vv, acc0);
            acc1 = __hfma2(*reinterpret_cast<__half2*>(&q[j].y), vv, acc1);
            acc2 = __hfma2(*reinterpret_cast<__half2*>(&q[j].z), vv, acc2);
            acc3 = __hfma2(*reinterpret_cast<__half2*>(&q[j].w), vv, acc3);
        }
    }
    float acc[8];
    {
        float2 f0 = __half22float2(acc0);
        float2 f1 = __half22float2(acc1);
        float2 f2 = __half22float2(acc2);
        float2 f3 = __half22float2(acc3);
        acc[0] = f0.x; acc[1] = f0.y; acc[2] = f1.x; acc[3] = f1.y;
        acc[4] = f2.x; acc[5] = f2.y; acc[6] = f3.x; acc[7] = f3.y;
    }
    #pragma unroll
    for (int o = 8; o < 32; o <<= 1) {
        #pragma unroll
        for (int d = 0; d < 8; ++d) acc[d] += __shfl_xor(acc[d], o);
    }
    const fvec4* nf = (const fvec4*)(noise + (size_t)row * DD);
    fvec4 na = __builtin_nontemporal_load(nf + sub * 2);
    fvec4 nb = __builtin_nontemporal_load(nf + sub * 2 + 1);
    float s = na.x * na.x + na.y * na.y + na.z * na.z + na.w * na.w
            + nb.x * nb.x + nb.y * nb.y + nb.z * nb.z + nb.w * nb.w;
    #pragma unroll
    for (int o = 1; o < 8; o <<= 1) s += __shfl_xor(s, o);
    float inv = EPS_ / fmaxf(sqrtf(s), 1e-12f);
    float nd_[8] = {na.x, na.y, na.z, na.w, nb.x, nb.y, nb.z, nb.w};
    float r[8];
    #pragma unroll
    for (int d = 0; d < 8; ++d) {
        float a = acc[d];
        float sg = (a > 0.f) ? 1.f : ((a < 0.f) ? -1.f : 0.f);
        r[d] = a + sg * nd_[d] * inv;
    }
    if (group == 0) {
        __half2 o0 = __floats2half2_rn(r[0], r[1]);
        __half2 o1 = __floats2half2_rn(r[2], r[3]);
        __half2 o2 = __floats2half2_rn(r[4], r[5]);
        __half2 o3 = __floats2half2_rn(r[6], r[7]);
        uint4 q;
        q.x = *reinterpret_cast<uint*>(&o0);
        q.y = *reinterpret_cast<uint*>(&o1);
        q.z = *reinterpret_cast<uint*>(&o2);
        q.w = *reinterpret_cast<uint*>(&o3);
        *(uint4*)((ushort*)y + ((size_t)row << 6) + (sub << 3)) = q;
    }
}

// ---------------- unique via flags, wave-aggregated; dual (y=0 users, y=1 items) ----------------
__global__ void unique_kernel(const int* __restrict__ users, const int* __restrict__ pos_items,
                              int* __restrict__ flags_u, int* __restrict__ flags_i,
                              int* __restrict__ ulist, int* __restrict__ ilist,
                              int* __restrict__ cnts) {
    int which = blockIdx.y;
    const int* in = which ? pos_items : users;
    int* flags = which ? flags_i : flags_u;
    int* list = which ? ilist : ulist;
    int* count = cnts + which;
    int t = blockIdx.x * blockDim.x + threadIdx.x;
    bool isnew = false;
    int u = 0;
    if (t < NBATCH) {
        u = in[t];
        isnew = (atomicExch(&flags[u], 1) == 0);
    }
    unsigned long long mask = __ballot(isnew);
    int nnew = __popcll(mask);
    int lane = threadIdx.x & 63;
    int base = 0;
    if (nnew) {
        int leader = __ffsll((long long)mask) - 1;
        if (lane == leader) base = atomicAdd(count, nnew);
        base = __shfl(base, leader);
        if (isnew) {
            int rank = __popcll(mask & ((1ull << lane) - 1ull));
            list[base + rank] = u;
        }
    }
}

// ---------------- gather + normalize -> fp16 V1/V2 (MFMA operands); dual via blockIdx.y ----------------
__global__ void gather_cl_kernel(const int* __restrict__ ulist, const int* __restrict__ ilist,
                                 const int* __restrict__ cnts,
                                 const __half* __restrict__ A, const __half* __restrict__ B,
                                 const __half* __restrict__ C,
                                 _Float16* __restrict__ V1, _Float16* __restrict__ V2,
                                 float* __restrict__ posv) {
    int which = blockIdx.y;
    const int* list = which ? ilist : ulist;
    int baseRow = which ? NU : 0;
    int cnt = cnts[which];
    _Float16* V1z = V1 + (size_t)which * NBATCH * DD;
    _Float16* V2z = V2 + (size_t)which * NBATCH * DD;
    float* posz = posv + which * NBATCH;
    int gid = blockIdx.x * blockDim.x + threadIdx.x;
    int s = gid >> 6;
    int lane = gid & 63;
    if (s >= NBATCH) return;
    float v1 = 0.f, v2 = 0.f;
    if (s < cnt) {
        size_t r = (size_t)(baseRow + list[s]) * DD + lane;
        v1 = ((float)A[r] + (float)B[r] + (float)C[r]) * (1.f / 3.f);
        v2 = (float)B[r];
    }
    float s1 = v1 * v1, s2 = v2 * v2;
    #pragma unroll
    for (int o = 32; o > 0; o >>= 1) { s1 += __shfl_xor(s1, o); s2 += __shfl_xor(s2, o); }
    v1 = v1 / fmaxf(sqrtf(s1), 1e-12f);
    v2 = v2 / fmaxf(sqrtf(s2), 1e-12f);
    V1z[s * DD + lane] = (_Float16)v1;
    V2z[s * DD + lane] = (_Float16)v2;
    float d = v1 * v2;
    #pragma unroll
    for (int o = 32; o > 0; o >>= 1) d += __shfl_xor(d, o);
    if (lane == 0) posz[s] = __expf(d * INV_TEMP);
}

// ---------------- ttl via MFMA: wave = 16-row i-tile x 256-col j-chunk, no LDS ----------------
__global__ void ttl_mfma_kernel(const _Float16* __restrict__ V1, const _Float16* __restrict__ V2,
                                const int* __restrict__ cnts, float* __restrict__ ttl) {
    int z = blockIdx.z;
    const _Float16* Az = V1 + (size_t)z * NBATCH * DD;
    const _Float16* Bz = V2 + (size_t)z * NBATCH * DD;
    float* ttlz = ttl + z * NBATCH;
    int cnt = cnts[z];
    int wave = threadIdx.x >> 6;
    int lane = threadIdx.x & 63;
    int n = lane & 15;
    int quad = lane >> 4;
    int itile = blockIdx.x * 4 + wave;
    int i0 = itile << 4;
    const _Float16* arow = Az + (size_t)(i0 + n) * DD + quad * 8;
    half8 a0 = *(const half8*)(arow);
    half8 a1 = *(const half8*)(arow + 32);
    float rs0 = 0.f, rs1 = 0.f, rs2 = 0.f, rs3 = 0.f;
    int jt0 = blockIdx.y * 16;
    int jtEnd = min(jt0 + 16, (cnt + 15) >> 4);
    for (int jt = jt0; jt < jtEnd; ++jt) {
        int j0 = jt << 4;
        const _Float16* brow = Bz + (size_t)(j0 + n) * DD + quad * 8;
        half8 b0 = *(const half8*)(brow);
        half8 b1 = *(const half8*)(brow + 32);
        floatx4 acc = {0.f, 0.f, 0.f, 0.f};
        acc = __builtin_amdgcn_mfma_f32_16x16x32_f16(a0, b0, acc, 0, 0, 0);
        acc = __builtin_amdgcn_mfma_f32_16x16x32_f16(a1, b1, acc, 0, 0, 0);
        bool valid = (j0 + n) < cnt;
        rs0 += valid ? __expf(acc[0] * INV_TEMP) : 0.f;
        rs1 += valid ? __expf(acc[1] * INV_TEMP) : 0.f;
        rs2 += valid ? __expf(acc[2] * INV_TEMP) : 0.f;
        rs3 += valid ? __expf(acc[3] * INV_TEMP) : 0.f;
    }
    #pragma unroll
    for (int o = 1; o < 16; o <<= 1) {
        rs0 += __shfl_xor(rs0, o);
        rs1 += __shfl_xor(rs1, o);
        rs2 += __shfl_xor(rs2, o);
        rs3 += __shfl_xor(rs3, o);
    }
    if (n == 0) {
        int r0 = i0 + quad * 4;
        atomicAdd(&ttlz[r0 + 0], rs0);
        atomicAdd(&ttlz[r0 + 1], rs1);
        atomicAdd(&ttlz[r0 + 2], rs2);
        atomicAdd(&ttlz[r0 + 3], rs3);
    }
}

// ---------------- BPR + reg: block of 4 waves -> one float2 partial ----------------
__global__ void bpr_kernel(const int* __restrict__ users, const int* __restrict__ pos,
                           const int* __restrict__ neg,
                           const __half* __restrict__ A, const __half* __restrict__ B,
                           const __half* __restrict__ C,
                           const float* __restrict__ user_emb, const float* __restrict__ item_emb,
                           float2* __restrict__ partials) {
    __shared__ float2 wp[4];
    int gid = blockIdx.x * blockDim.x + threadIdx.x;
    int b = gid >> 6;
    int lane = gid & 63;
    int wid = (threadIdx.x >> 6);
    float lg = 0.f, rgsum = 0.f;
    if (b < NBATCH) {
        int u = users[b], p = pos[b], n = neg[b];
        size_t ru = (size_t)u * DD + lane;
        size_t rp = (size_t)(NU + p) * DD + lane;
        size_t rn = (size_t)(NU + n) * DD + lane;
        float ue = ((float)A[ru] + (float)B[ru] + (float)C[ru]) * (1.f / 3.f);
        float pe = ((float)A[rp] + (float)B[rp] + (float)C[rp]) * (1.f / 3.f);
        float ne = ((float)A[rn] + (float)B[rn] + (float)C[rn]) * (1.f / 3.f);
        float su = ue * ue, sp = pe * pe, sn = ne * ne, dp = ue * pe, dn = ue * ne;
        float u0 = user_emb[(size_t)u * DD + lane];
        float p0 = item_emb[(size_t)p * DD + lane];
        float n0 = item_emb[(size_t)n * DD + lane];
        float rg = u0 * u0 + p0 * p0 + n0 * n0;
        #pragma unroll
        for (int o = 32; o > 0; o >>= 1) {
            su += __shfl_xor(su, o); sp += __shfl_xor(sp, o); sn += __shfl_xor(sn, o);
            dp += __shfl_xor(dp, o); dn += __shfl_xor(dn, o); rg += __shfl_xor(rg, o);
        }
        float nu = fmaxf(sqrtf(su), 1e-12f);
        float np_ = fmaxf(sqrtf(sp), 1e-12f);
        float nn_ = fmaxf(sqrtf(sn), 1e-12f);
        float ps = dp / (nu * np_);
        float ns = dn / (nu * nn_);
        float xx = ps - ns;
        float sig = 1.f / (1.f + __expf(-xx));
        lg = logf(sig + 1e-6f);
        rgsum = rg;
    }
    if (lane == 0) wp[wid] = make_float2(lg, rgsum);
    __syncthreads();
    if (threadIdx.x == 0) {
        float2 s = wp[0];
        s.x += wp[1].x + wp[2].x + wp[3].x;
        s.y += wp[1].y + wp[2].y + wp[3].y;
        partials[blockIdx.x] = s;
    }
}

// ---------------- finalize: bpr partials + cl terms, all in one block ----------------
__global__ void finalize_kernel(const float2* __restrict__ partials,
                                const float* __restrict__ posv, const float* __restrict__ ttlv,
                                const int* __restrict__ cnts, float* __restrict__ out) {
    __shared__ float4 wsum[16];
    int t = threadIdx.x;   // 1024
    float mf = 0.f, rg = 0.f;
    if (t < BPR_BLOCKS) { float2 v = partials[t]; mf = v.x; rg = v.y; }
    int c0 = cnts[0], c1 = cnts[1];
    float clu = 0.f, cli = 0.f;
    for (int k = t; k < NBATCH; k += 1024) {
        if (k < c0) clu += -logf(posv[k] / ttlv[k] + 1e-5f);
        if (k < c1) cli += -logf(posv[NBATCH + k] / ttlv[NBATCH + k] + 1e-5f);
    }
    float4 v4 = make_float4(mf, rg, clu, cli);
    #pragma unroll
    for (int o = 32; o > 0; o >>= 1) {
        v4.x += __shfl_xor(v4.x, o); v4.y += __shfl_xor(v4.y, o);
        v4.z += __shfl_xor(v4.z, o); v4.w += __shfl_xor(v4.w, o);
    }
    if ((t & 63) == 0) wsum[t >> 6] = v4;
    __syncthreads();
    if (t == 0) {
        float a = 0.f, b = 0.f, c = 0.f, d = 0.f;
        #pragma unroll
        for (int k = 0; k < 16; ++k) { a += wsum[k].x; b += wsum[k].y; c += wsum[k].z; d += wsum[k].w; }
        out[0] = -a / (float)NBATCH;
        out[1] = 0.2f * (c / (float)c0 + d / (float)c1);
        out[2] = 1e-4f * 0.5f * b / (float)NBATCH;
    }
}

extern "C" void kernel_launch(void* const* d_in, const int* in_sizes, int n_in,
                              void* d_out, int out_size, void* d_ws, size_t ws_size,
                              hipStream_t stream) {
    const int*   users     = (const int*)d_in[0];
    const int*   pos_items = (const int*)d_in[1];
    const int*   neg_items = (const int*)d_in[2];
    const float* user_emb  = (const float*)d_in[3];
    const float* item_emb  = (const float*)d_in[4];
    const int*   rows      = (const int*)d_in[5];
    const int*   cols      = (const int*)d_in[6];
    const float* vals      = (const float*)d_in[7];
    const float* noise     = (const float*)d_in[8];
    float* out = (float*)d_out;
    const int E = in_sizes[5];

    // ---- workspace carve (256B aligned) ----
    char* w = (char*)d_ws;
    size_t off = 0;
    auto carve = [&](size_t bytes) { char* p = w + off; off = (off + bytes + 255) & ~(size_t)255; return p; };
    __half* bufX = (__half*)carve(ND * 2);
    __half* bufA = (__half*)carve(ND * 2);
    __half* bufB = (__half*)carve(ND * 2);
    __half* bufC = (__half*)carve(ND * 2);
    int2*  bedges  = (int2*)carve((size_t)NCB * CAP * 8);
    int2*  edges   = (int2*)carve((size_t)NCB * CAP * 8);
    int*   rstart  = (int*)carve(NT * 4);
    int*   deg     = (int*)carve(NT * 4);
    // ---- contiguous zero region ----
    char* zstart = w + off;
    int*   ccur    = (int*)carve(NCB * 4);
    int*   cnts    = (int*)carve(2 * 4);
    float* ttl     = (float*)carve(2 * NBATCH * 4);
    int*   flags_u = (int*)carve(NU * 4);
    int*   flags_i = (int*)carve(NI * 4);
    size_t zbytes = (size_t)((w + off) - zstart);
    // ---- end zero region ----
    int* ulist   = (int*)carve(NBATCH * 4);
    int* ilist   = (int*)carve(NBATCH * 4);
    _Float16* V1 = (_Float16*)carve((size_t)2 * NBATCH * DD * 2);
    _Float16* V2 = (_Float16*)carve((size_t)2 * NBATCH * DD * 2);
    float* posv = (float*)carve(2 * NBATCH * 4);
    float2* bpr_part = (float2*)carve(BPR_BLOCKS * 8);

    hipMemsetAsync(zstart, 0, zbytes, stream);

    const int nTiles = (E + TILE - 1) / TILE;
    const int rowBlocks  = (NT * 32 + 255) / 256;       // 2 rows per wave -> 12500 blocks
    const int slotBlocks = (NBATCH * DD + 255) / 256;   // 1024
    const int cvtBlocks  = (int)((ND / 4 + 255) / 256);

    // ---- edge sort: LDS-staged coarse counting sort -> LDS-staged fine sort ----
    coarse_bin_kernel<<<nTiles, 1024, 0, stream>>>(rows, cols, vals, E, ccur, bedges);
    fine_sort_kernel<<<NCB, 512, 0, stream>>>(ccur, bedges, edges, rstart, deg);

    // ---- fp16 input concat ----
    concat_half_kernel<<<cvtBlocks, 256, 0, stream>>>(user_emb, item_emb, bufX);

    // ---- 3 propagation layers (perturb fused) ----
    spmm_csr_kernel<<<rowBlocks, 256, 0, stream>>>(rstart, deg, edges, bufX, noise + 0 * ND, bufB);
    spmm_csr_kernel<<<rowBlocks, 256, 0, stream>>>(rstart, deg, edges, bufB, noise + 1 * ND, bufC);
    spmm_csr_kernel<<<rowBlocks, 256, 0, stream>>>(rstart, deg, edges, bufC, noise + 2 * ND, bufA);

    // ---- unique (dual) ----
    dim3 ugrid((NBATCH + 255) / 256, 2);
    unique_kernel<<<ugrid, 256, 0, stream>>>(users, pos_items, flags_u, flags_i, ulist, ilist, cnts);

    // ---- gather + normalize + pos scores (dual) ----
    dim3 ggrid(slotBlocks, 2);
    gather_cl_kernel<<<ggrid, 256, 0, stream>>>(ulist, ilist, cnts, bufA, bufB, bufC, V1, V2, posv);

    // ---- ttl via MFMA: grid (i-tiles/4, j-chunks, 2) ----
    dim3 tgrid(NBATCH / 16 / 4, 16, 2);
    ttl_mfma_kernel<<<tgrid, 256, 0, stream>>>(V1, V2, cnts, ttl);

    // ---- BPR + reg (two-stage) ----
    bpr_kernel<<<BPR_BLOCKS, 256, 0, stream>>>(users, pos_items, neg_items, bufA, bufB, bufC,
                                               user_emb, item_emb, bpr_part);

    // ---- finalize (absorbs cl reduction) ----
    finalize_kernel<<<1, 1024, 0, stream>>>(bpr_part, posv, ttl, cnts, out);
}

// Round 11
// 415.041 us; speedup vs baseline: 1.0248x; 1.0248x over previous
//
#include <hip/hip_runtime.h>
#include <hip/hip_fp16.h>
#include <math.h>

#define NU 50000
#define NI 50000
#define NT 100000
#define DD 64
#define NBATCH 4096
#define INV_TEMP 5.0f
#define EPS_ 0.2f

#define CBR 256                            // rows per coarse bucket
#define CBR_SH 8
#define NCB ((NT + CBR - 1) / CBR)         // 391
#define CAP 9200                           // fixed edge capacity per bucket (mean 8184, ~11 sigma)
#define TILE 8192                          // edges per phase-1 block (staged in LDS)
#define NWSUM ((NCB + 63) / 64)            // 7
#define ND ((long long)NT * DD)            // 6,400,000
#define BPR_BLOCKS (NBATCH / 4)            // 1024 partials

typedef _Float16 half8 __attribute__((ext_vector_type(8)));
typedef float floatx4 __attribute__((ext_vector_type(4)));

// ---------------- phase 1: block-level counting sort into fixed-capacity coarse buckets ----------------
// LDS-staged write-combining. packed out: x = (rl8 << 24) | (col << 7) [col pre-shifted to byte offset],
// y = half2(val)   [R3/R6-proven config]
__global__ __launch_bounds__(1024, 8) void coarse_bin_kernel(
        const int* __restrict__ rows, const int* __restrict__ cols,
        const float* __restrict__ vals, int E,
        int* __restrict__ ccur, int2* __restrict__ bedges) {
    __shared__ int  sx[TILE];       // (rl<<24)|(col<<7)       32 KB
    __shared__ uint svc[TILE];      // (cb<<16)|half(val)      32 KB
    __shared__ int  h[NCB];         // hist -> lcur
    __shared__ int  lstart[NCB];    // exclusive scan
    __shared__ int  gbase[NCB];     // global run base
    __shared__ int  wsum[NWSUM];
    int t = threadIdx.x;   // 1024
    for (int k = t; k < NCB; k += 1024) h[k] = 0;
    __syncthreads();
    int base = blockIdx.x * TILE;
    int cnt = min(TILE, E - base);
    // pass A: load tile into registers + LDS histogram
    int   r_[8];
    int   c_[8];
    float v_[8];
    #pragma unroll
    for (int it = 0; it < 8; ++it) {
        int i = it * 1024 + t;
        bool ok = i < cnt;
        int e = base + i;
        r_[it] = ok ? rows[e] : 0;
        c_[it] = ok ? cols[e] : 0;
        v_[it] = ok ? vals[e] : 0.f;
        if (ok) atomicAdd(&h[r_[it] >> CBR_SH], 1);
    }
    __syncthreads();
    // exclusive scan of h[0..NCB) -> lstart; reserve global runs
    int lane = t & 63, wid = t >> 6;
    int v = (t < NCB) ? h[t] : 0;
    int x = v;
    #pragma unroll
    for (int o = 1; o < 64; o <<= 1) { int y = __shfl_up(x, o); if (lane >= o) x += y; }
    if (lane == 63 && wid < NWSUM) wsum[wid] = x;
    __syncthreads();
    if (t == 0) {
        int s = 0;
        #pragma unroll
        for (int k = 0; k < NWSUM; ++k) { int tmp = wsum[k]; wsum[k] = s; s += tmp; }
    }
    __syncthreads();
    if (t < NCB) {
        int ex = x - v + wsum[wid];
        lstart[t] = ex;
        gbase[t] = t * CAP + (v ? atomicAdd(&ccur[t], v) : 0);
        h[t] = ex;   // becomes lcur
    }
    __syncthreads();
    // pass B: scatter into LDS (counting-sort placement)
    #pragma unroll
    for (int it = 0; it < 8; ++it) {
        int i = it * 1024 + t;
        if (i < cnt) {
            int r = r_[it];
            int cb = r >> CBR_SH;
            int p = atomicAdd(&h[cb], 1);
            sx[p] = ((r & (CBR - 1)) << 24) | (c_[it] << 7);
            __half hv = __float2half(v_[it]);
            ushort hb = *reinterpret_cast<ushort*>(&hv);
            svc[p] = ((uint)cb << 16) | (uint)hb;
        }
    }
    __syncthreads();
    // pass C: coalesced write-out in staged (bucket-sorted) order
    for (int i = t; i < cnt; i += 1024) {
        uint vc = svc[i];
        int cb = (int)(vc >> 16);
        uint hb = vc & 0xFFFFu;
        int dst = gbase[cb] + (i - lstart[cb]);
        bedges[dst] = make_int2(sx[i], (int)(hb | (hb << 16)));
    }
}

// ---------------- phase 2: per-bucket row sort, LDS-staged for coalesced writeout ----------------
// final edges: x = col<<7 (byte offset), y = half2(val)
__global__ __launch_bounds__(1024, 2) void fine_sort_kernel(
        const int* __restrict__ ccur, const int2* __restrict__ bedges,
        int2* __restrict__ edges, int* __restrict__ rstart,
        int* __restrict__ deg) {
    __shared__ int2 sedge[CAP];     // 73.6 KB staged sorted bucket
    __shared__ int h[CBR];
    __shared__ int lcur[CBR];
    __shared__ int wsum[CBR / 64];
    int b = blockIdx.x;
    int t = threadIdx.x;   // 1024
    int r0 = b * CBR;
    int nrows = min(CBR, NT - r0);
    if (t < CBR) h[t] = 0;
    __syncthreads();
    int e0 = b * CAP;
    int ec = ccur[b];
    int e1 = e0 + ec;
    for (int k = e0 + t; k < e1; k += 1024) atomicAdd(&h[((uint)bedges[k].x) >> 24], 1);
    __syncthreads();
    int v = 0, x = 0;
    int lane = t & 63, wid = t >> 6;
    if (t < CBR) {
        v = h[t];
        x = v;
        #pragma unroll
        for (int o = 1; o < 64; o <<= 1) { int y = __shfl_up(x, o); if (lane >= o) x += y; }
        if (lane == 63) wsum[wid] = x;
    }
    __syncthreads();
    if (t == 0) {
        int s = 0;
        #pragma unroll
        for (int k = 0; k < CBR / 64; ++k) { int tmp = wsum[k]; wsum[k] = s; s += tmp; }
    }
    __syncthreads();
    if (t < CBR) {
        int ex = x - v + wsum[wid];          // local (0-based) start
        if (t < nrows) { rstart[r0 + t] = e0 + ex; deg[r0 + t] = v; }
        lcur[t] = ex;
    }
    __syncthreads();
    // scatter into LDS in row-sorted order
    for (int k = e0 + t; k < e1; k += 1024) {
        int2 ed = bedges[k];
        int rl = (int)(((uint)ed.x) >> 24);
        int p = atomicAdd(&lcur[rl], 1);
        if (p < CAP) sedge[p] = make_int2(ed.x & 0xFFFFFF, ed.y);
    }
    __syncthreads();
    // fully-coalesced streaming writeout
    for (int i = t; i < ec; i += 1024) edges[e0 + i] = sedge[i];
}

// ---------------- fp32 concat -> fp16 (4 elems/thread) ----------------
__global__ void concat_half_kernel(const float* __restrict__ u, const float* __restrict__ it,
                                   __half* __restrict__ x0) {
    long long i = ((long long)blockIdx.x * 256 + threadIdx.x) * 4;
    if (i >= ND) return;
    long long half1 = (long long)NU * DD;
    float4 v = (i < half1) ? *(const float4*)(u + i) : *(const float4*)(it + (i - half1));
    __half2 h01 = __floats2half2_rn(v.x, v.y);
    __half2 h23 = __floats2half2_rn(v.z, v.w);
    uint2 q;
    q.x = *reinterpret_cast<uint*>(&h01);
    q.y = *reinterpret_cast<uint*>(&h23);
    *(uint2*)((ushort*)x0 + i) = q;
}

// ---------------- SpMM: 2 rows per wave (32 lanes/row), 8 staged edges/group (R6-proven) ----------------
__global__ void spmm_csr_kernel(const int* __restrict__ rstart, const int* __restrict__ deg,
                                const int2* __restrict__ edges,
                                const __half* __restrict__ x, const float* __restrict__ noise,
                                __half* __restrict__ y) {
    int gid = blockIdx.x * blockDim.x + threadIdx.x;
    int row = gid >> 5;        // one row per 32 lanes
    int l32 = gid & 31;
    int group = l32 >> 3;      // 0..3: edge-slot group within the row
    int sub = l32 & 7;         // dims sub*8 .. sub*8+7
    int subo = sub << 4;       // byte offset of this lane's 16B segment
    if (row >= NT) return;
    int s0 = rstart[row];
    int dg = deg[row];
    int dgl = dg - group;      // edge base+group+4j valid iff base+4j < dgl
    const char* xb = (const char*)x;
    __half2 acc0 = __half2(__half(0.f), __half(0.f));
    __half2 acc1 = acc0, acc2 = acc0, acc3 = acc0;
    for (int base = 0; base < dg; base += 32) {
        int2 e[8];
        #pragma unroll
        for (int j = 0; j < 8; ++j) {
            e[j] = edges[s0 + min(base + group + 4 * j, dg - 1)];
        }
        uint4 q[8];
        #pragma unroll
        for (int j = 0; j < 8; ++j) {
            q[j] = *(const uint4*)(xb + (uint)(e[j].x + subo));
        }
        #pragma unroll
        for (int j = 0; j < 8; ++j) {
            int vb = (base + 4 * j < dgl) ? e[j].y : 0;
            __half2 vv = *reinterpret_cast<__half2*>(&vb);
            acc0 = __hfma2(*reinterpret_cast<__half2*>(&q[j].x), vv, acc0);
            acc1 = __hfma2(*reinterpret_cast<__half2*>(&q[j].y), vv, acc1);
            acc2 = __hfma2(*reinterpret_cast<__half2*>(&q[j].z), vv, acc2);
            acc3 = __hfma2(*reinterpret_cast<__half2*>(&q[j].w), vv, acc3);
        }
    }
    float acc[8];
    {
        float2 f0 = __half22float2(acc0);
        float2 f1 = __half22float2(acc1);
        float2 f2 = __half22float2(acc2);
        float2 f3 = __half22float2(acc3);
        acc[0] = f0.x; acc[1] = f0.y; acc[2] = f1.x; acc[3] = f1.y;
        acc[4] = f2.x; acc[5] = f2.y; acc[6] = f3.x; acc[7] = f3.y;
    }
    // reduce across the 4 groups (lane bits 3..4; stays within the 32-lane row half)
    #pragma unroll
    for (int o = 8; o < 32; o <<= 1) {
        #pragma unroll
        for (int d = 0; d < 8; ++d) acc[d] += __shfl_xor(acc[d], o);
    }
    // perturb
    const float4* nf = (const float4*)(noise + (size_t)row * DD);
    float4 na = nf[sub * 2];
    float4 nb = nf[sub * 2 + 1];
    float s = na.x * na.x + na.y * na.y + na.z * na.z + na.w * na.w
            + nb.x * nb.x + nb.y * nb.y + nb.z * nb.z + nb.w * nb.w;
    #pragma unroll
    for (int o = 1; o < 8; o <<= 1) s += __shfl_xor(s, o);
    float inv = EPS_ / fmaxf(sqrtf(s), 1e-12f);
    float nd_[8] = {na.x, na.y, na.z, na.w, nb.x, nb.y, nb.z, nb.w};
    float r[8];
    #pragma unroll
    for (int d = 0; d < 8; ++d) {
        float a = acc[d];
        float sg = (a > 0.f) ? 1.f : ((a < 0.f) ? -1.f : 0.f);
        r[d] = a + sg * nd_[d] * inv;
    }
    if (group == 0) {
        __half2 o0 = __floats2half2_rn(r[0], r[1]);
        __half2 o1 = __floats2half2_rn(r[2], r[3]);
        __half2 o2 = __floats2half2_rn(r[4], r[5]);
        __half2 o3 = __floats2half2_rn(r[6], r[7]);
        uint4 q;
        q.x = *reinterpret_cast<uint*>(&o0);
        q.y = *reinterpret_cast<uint*>(&o1);
        q.z = *reinterpret_cast<uint*>(&o2);
        q.w = *reinterpret_cast<uint*>(&o3);
        *(uint4*)((ushort*)y + ((size_t)row << 6) + (sub << 3)) = q;
    }
}

// ---------------- unique via flags, wave-aggregated; dual (y=0 users, y=1 items) ----------------
__global__ void unique_kernel(const int* __restrict__ users, const int* __restrict__ pos_items,
                              int* __restrict__ flags_u, int* __restrict__ flags_i,
                              int* __restrict__ ulist, int* __restrict__ ilist,
                              int* __restrict__ cnts) {
    int which = blockIdx.y;
    const int* in = which ? pos_items : users;
    int* flags = which ? flags_i : flags_u;
    int* list = which ? ilist : ulist;
    int* count = cnts + which;
    int t = blockIdx.x * blockDim.x + threadIdx.x;
    bool isnew = false;
    int u = 0;
    if (t < NBATCH) {
        u = in[t];
        isnew = (atomicExch(&flags[u], 1) == 0);
    }
    unsigned long long mask = __ballot(isnew);
    int nnew = __popcll(mask);
    int lane = threadIdx.x & 63;
    int base = 0;
    if (nnew) {
        int leader = __ffsll((long long)mask) - 1;
        if (lane == leader) base = atomicAdd(count, nnew);
        base = __shfl(base, leader);
        if (isnew) {
            int rank = __popcll(mask & ((1ull << lane) - 1ull));
            list[base + rank] = u;
        }
    }
}

// ---------------- gather + normalize -> fp16 V1/V2 (MFMA operands); dual via blockIdx.y ----------------
__global__ void gather_cl_kernel(const int* __restrict__ ulist, const int* __restrict__ ilist,
                                 const int* __restrict__ cnts,
                                 const __half* __restrict__ A, const __half* __restrict__ B,
                                 const __half* __restrict__ C,
                                 _Float16* __restrict__ V1, _Float16* __restrict__ V2,
                                 float* __restrict__ posv) {
    int which = blockIdx.y;
    const int* list = which ? ilist : ulist;
    int baseRow = which ? NU : 0;
    int cnt = cnts[which];
    _Float16* V1z = V1 + (size_t)which * NBATCH * DD;
    _Float16* V2z = V2 + (size_t)which * NBATCH * DD;
    float* posz = posv + which * NBATCH;
    int gid = blockIdx.x * blockDim.x + threadIdx.x;
    int s = gid >> 6;
    int lane = gid & 63;
    if (s >= NBATCH) return;
    float v1 = 0.f, v2 = 0.f;
    if (s < cnt) {
        size_t r = (size_t)(baseRow + list[s]) * DD + lane;
        v1 = ((float)A[r] + (float)B[r] + (float)C[r]) * (1.f / 3.f);
        v2 = (float)B[r];
    }
    float s1 = v1 * v1, s2 = v2 * v2;
    #pragma unroll
    for (int o = 32; o > 0; o >>= 1) { s1 += __shfl_xor(s1, o); s2 += __shfl_xor(s2, o); }
    v1 = v1 / fmaxf(sqrtf(s1), 1e-12f);
    v2 = v2 / fmaxf(sqrtf(s2), 1e-12f);
    V1z[s * DD + lane] = (_Float16)v1;
    V2z[s * DD + lane] = (_Float16)v2;
    float d = v1 * v2;
    #pragma unroll
    for (int o = 32; o > 0; o >>= 1) d += __shfl_xor(d, o);
    if (lane == 0) posz[s] = __expf(d * INV_TEMP);
}

// ---------------- ttl via MFMA: wave = 16-row i-tile x 256-col j-chunk, no LDS ----------------
__global__ void ttl_mfma_kernel(const _Float16* __restrict__ V1, const _Float16* __restrict__ V2,
                                const int* __restrict__ cnts, float* __restrict__ ttl) {
    int z = blockIdx.z;
    const _Float16* Az = V1 + (size_t)z * NBATCH * DD;
    const _Float16* Bz = V2 + (size_t)z * NBATCH * DD;
    float* ttlz = ttl + z * NBATCH;
    int cnt = cnts[z];
    int wave = threadIdx.x >> 6;
    int lane = threadIdx.x & 63;
    int n = lane & 15;
    int quad = lane >> 4;
    int itile = blockIdx.x * 4 + wave;
    int i0 = itile << 4;
    const _Float16* arow = Az + (size_t)(i0 + n) * DD + quad * 8;
    half8 a0 = *(const half8*)(arow);
    half8 a1 = *(const half8*)(arow + 32);
    float rs0 = 0.f, rs1 = 0.f, rs2 = 0.f, rs3 = 0.f;
    int jt0 = blockIdx.y * 16;
    int jtEnd = min(jt0 + 16, (cnt + 15) >> 4);
    for (int jt = jt0; jt < jtEnd; ++jt) {
        int j0 = jt << 4;
        const _Float16* brow = Bz + (size_t)(j0 + n) * DD + quad * 8;
        half8 b0 = *(const half8*)(brow);
        half8 b1 = *(const half8*)(brow + 32);
        floatx4 acc = {0.f, 0.f, 0.f, 0.f};
        acc = __builtin_amdgcn_mfma_f32_16x16x32_f16(a0, b0, acc, 0, 0, 0);
        acc = __builtin_amdgcn_mfma_f32_16x16x32_f16(a1, b1, acc, 0, 0, 0);
        bool valid = (j0 + n) < cnt;
        rs0 += valid ? __expf(acc[0] * INV_TEMP) : 0.f;
        rs1 += valid ? __expf(acc[1] * INV_TEMP) : 0.f;
        rs2 += valid ? __expf(acc[2] * INV_TEMP) : 0.f;
        rs3 += valid ? __expf(acc[3] * INV_TEMP) : 0.f;
    }
    #pragma unroll
    for (int o = 1; o < 16; o <<= 1) {
        rs0 += __shfl_xor(rs0, o);
        rs1 += __shfl_xor(rs1, o);
        rs2 += __shfl_xor(rs2, o);
        rs3 += __shfl_xor(rs3, o);
    }
    if (n == 0) {
        int r0 = i0 + quad * 4;
        atomicAdd(&ttlz[r0 + 0], rs0);
        atomicAdd(&ttlz[r0 + 1], rs1);
        atomicAdd(&ttlz[r0 + 2], rs2);
        atomicAdd(&ttlz[r0 + 3], rs3);
    }
}

// ---------------- BPR + reg: block of 4 waves -> one float2 partial ----------------
__global__ void bpr_kernel(const int* __restrict__ users, const int* __restrict__ pos,
                           const int* __restrict__ neg,
                           const __half* __restrict__ A, const __half* __restrict__ B,
                           const __half* __restrict__ C,
                           const float* __restrict__ user_emb, const float* __restrict__ item_emb,
                           float2* __restrict__ partials) {
    __shared__ float2 wp[4];
    int gid = blockIdx.x * blockDim.x + threadIdx.x;
    int b = gid >> 6;
    int lane = gid & 63;
    int wid = (threadIdx.x >> 6);
    float lg = 0.f, rgsum = 0.f;
    if (b < NBATCH) {
        int u = users[b], p = pos[b], n = neg[b];
        size_t ru = (size_t)u * DD + lane;
        size_t rp = (size_t)(NU + p) * DD + lane;
        size_t rn = (size_t)(NU + n) * DD + lane;
        float ue = ((float)A[ru] + (float)B[ru] + (float)C[ru]) * (1.f / 3.f);
        float pe = ((float)A[rp] + (float)B[rp] + (float)C[rp]) * (1.f / 3.f);
        float ne = ((float)A[rn] + (float)B[rn] + (float)C[rn]) * (1.f / 3.f);
        float su = ue * ue, sp = pe * pe, sn = ne * ne, dp = ue * pe, dn = ue * ne;
        float u0 = user_emb[(size_t)u * DD + lane];
        float p0 = item_emb[(size_t)p * DD + lane];
        float n0 = item_emb[(size_t)n * DD + lane];
        float rg = u0 * u0 + p0 * p0 + n0 * n0;
        #pragma unroll
        for (int o = 32; o > 0; o >>= 1) {
            su += __shfl_xor(su, o); sp += __shfl_xor(sp, o); sn += __shfl_xor(sn, o);
            dp += __shfl_xor(dp, o); dn += __shfl_xor(dn, o); rg += __shfl_xor(rg, o);
        }
        float nu = fmaxf(sqrtf(su), 1e-12f);
        float np_ = fmaxf(sqrtf(sp), 1e-12f);
        float nn_ = fmaxf(sqrtf(sn), 1e-12f);
        float ps = dp / (nu * np_);
        float ns = dn / (nu * nn_);
        float xx = ps - ns;
        float sig = 1.f / (1.f + __expf(-xx));
        lg = logf(sig + 1e-6f);
        rgsum = rg;
    }
    if (lane == 0) wp[wid] = make_float2(lg, rgsum);
    __syncthreads();
    if (threadIdx.x == 0) {
        float2 s = wp[0];
        s.x += wp[1].x + wp[2].x + wp[3].x;
        s.y += wp[1].y + wp[2].y + wp[3].y;
        partials[blockIdx.x] = s;
    }
}

// ---------------- finalize: bpr partials + cl terms, all in one block ----------------
__global__ void finalize_kernel(const float2* __restrict__ partials,
                                const float* __restrict__ posv, const float* __restrict__ ttlv,
                                const int* __restrict__ cnts, float* __restrict__ out) {
    __shared__ float4 wsum[16];
    int t = threadIdx.x;   // 1024
    float mf = 0.f, rg = 0.f;
    if (t < BPR_BLOCKS) { float2 v = partials[t]; mf = v.x; rg = v.y; }
    int c0 = cnts[0], c1 = cnts[1];
    float clu = 0.f, cli = 0.f;
    for (int k = t; k < NBATCH; k += 1024) {
        if (k < c0) clu += -logf(posv[k] / ttlv[k] + 1e-5f);
        if (k < c1) cli += -logf(posv[NBATCH + k] / ttlv[NBATCH + k] + 1e-5f);
    }
    float4 v4 = make_float4(mf, rg, clu, cli);
    #pragma unroll
    for (int o = 32; o > 0; o >>= 1) {
        v4.x += __shfl_xor(v4.x, o); v4.y += __shfl_xor(v4.y, o);
        v4.z += __shfl_xor(v4.z, o); v4.w += __shfl_xor(v4.w, o);
    }
    if ((t & 63) == 0) wsum[t >> 6] = v4;
    __syncthreads();
    if (t == 0) {
        float a = 0.f, b = 0.f, c = 0.f, d = 0.f;
        #pragma unroll
        for (int k = 0; k < 16; ++k) { a += wsum[k].x; b += wsum[k].y; c += wsum[k].z; d += wsum[k].w; }
        out[0] = -a / (float)NBATCH;
        out[1] = 0.2f * (c / (float)c0 + d / (float)c1);
        out[2] = 1e-4f * 0.5f * b / (float)NBATCH;
    }
}

extern "C" void kernel_launch(void* const* d_in, const int* in_sizes, int n_in,
                              void* d_out, int out_size, void* d_ws, size_t ws_size,
                              hipStream_t stream) {
    const int*   users     = (const int*)d_in[0];
    const int*   pos_items = (const int*)d_in[1];
    const int*   neg_items = (const int*)d_in[2];
    const float* user_emb  = (const float*)d_in[3];
    const float* item_emb  = (const float*)d_in[4];
    const int*   rows      = (const int*)d_in[5];
    const int*   cols      = (const int*)d_in[6];
    const float* vals      = (const float*)d_in[7];
    const float* noise     = (const float*)d_in[8];
    float* out = (float*)d_out;
    const int E = in_sizes[5];

    // ---- workspace carve (256B aligned) ----
    char* w = (char*)d_ws;
    size_t off = 0;
    auto carve = [&](size_t bytes) { char* p = w + off; off = (off + bytes + 255) & ~(size_t)255; return p; };
    __half* bufX = (__half*)carve(ND * 2);
    __half* bufA = (__half*)carve(ND * 2);
    __half* bufB = (__half*)carve(ND * 2);
    __half* bufC = (__half*)carve(ND * 2);
    int2*  bedges  = (int2*)carve((size_t)NCB * CAP * 8);
    int2*  edges   = (int2*)carve((size_t)NCB * CAP * 8);
    int*   rstart  = (int*)carve(NT * 4);
    int*   deg     = (int*)carve(NT * 4);
    // ---- contiguous zero region ----
    char* zstart = w + off;
    int*   ccur    = (int*)carve(NCB * 4);
    int*   cnts    = (int*)carve(2 * 4);
    float* ttl     = (float*)carve(2 * NBATCH * 4);
    int*   flags_u = (int*)carve(NU * 4);
    int*   flags_i = (int*)carve(NI * 4);
    size_t zbytes = (size_t)((w + off) - zstart);
    // ---- end zero region ----
    int* ulist   = (int*)carve(NBATCH * 4);
    int* ilist   = (int*)carve(NBATCH * 4);
    _Float16* V1 = (_Float16*)carve((size_t)2 * NBATCH * DD * 2);
    _Float16* V2 = (_Float16*)carve((size_t)2 * NBATCH * DD * 2);
    float* posv = (float*)carve(2 * NBATCH * 4);
    float2* bpr_part = (float2*)carve(BPR_BLOCKS * 8);

    hipMemsetAsync(zstart, 0, zbytes, stream);

    const int nTiles = (E + TILE - 1) / TILE;
    const int rowBlocks  = (NT * 32 + 255) / 256;       // 2 rows per wave -> 12500 blocks
    const int slotBlocks = (NBATCH * DD + 255) / 256;   // 1024
    const int cvtBlocks  = (int)((ND / 4 + 255) / 256);

    // ---- edge sort: LDS-staged coarse counting sort -> LDS-staged fine sort ----
    coarse_bin_kernel<<<nTiles, 1024, 0, stream>>>(rows, cols, vals, E, ccur, bedges);
    fine_sort_kernel<<<NCB, 1024, 0, stream>>>(ccur, bedges, edges, rstart, deg);

    // ---- fp16 input concat ----
    concat_half_kernel<<<cvtBlocks, 256, 0, stream>>>(user_emb, item_emb, bufX);

    // ---- 3 propagation layers (perturb fused) ----
    spmm_csr_kernel<<<rowBlocks, 256, 0, stream>>>(rstart, deg, edges, bufX, noise + 0 * ND, bufB);
    spmm_csr_kernel<<<rowBlocks, 256, 0, stream>>>(rstart, deg, edges, bufB, noise + 1 * ND, bufC);
    spmm_csr_kernel<<<rowBlocks, 256, 0, stream>>>(rstart, deg, edges, bufC, noise + 2 * ND, bufA);

    // ---- unique (dual) ----
    dim3 ugrid((NBATCH + 255) / 256, 2);
    unique_kernel<<<ugrid, 256, 0, stream>>>(users, pos_items, flags_u, flags_i, ulist, ilist, cnts);

    // ---- gather + normalize + pos scores (dual) ----
    dim3 ggrid(slotBlocks, 2);
    gather_cl_kernel<<<ggrid, 256, 0, stream>>>(ulist, ilist, cnts, bufA, bufB, bufC, V1, V2, posv);

    // ---- ttl via MFMA: grid (i-tiles/4, j-chunks, 2) ----
    dim3 tgrid(NBATCH / 16 / 4, 16, 2);
    ttl_mfma_kernel<<<tgrid, 256, 0, stream>>>(V1, V2, cnts, ttl);

    // ---- BPR + reg (two-stage) ----
    bpr_kernel<<<BPR_BLOCKS, 256, 0, stream>>>(users, pos_items, neg_items, bufA, bufB, bufC,
                                               user_emb, item_emb, bpr_part);

    // ---- finalize (absorbs cl reduction) ----
    finalize_kernel<<<1, 1024, 0, stream>>>(bpr_part, posv, ttl, cnts, out);
}